// Round 8
// baseline (5749.661 us; speedup 1.0000x reference)
//
#include <hip/hip_runtime.h>
#include <math.h>

#define NB    4
#define NPER  8192
#define MPER  4096
#define NTOT  32768
#define MTOT  16384
#define COUT  128

// d_out layout (floats): new_x [16384*128] | new_pos [16384*3] | new_batch [16384]
#define NEWPOS_OFF 2097152
#define NEWB_OFF   2146304

// workspace layout (bytes); ~17 MB
#define WS_H     0u           // 32768*128*4 = 16777216
#define WS_SQP   16777216u    // 32768*4
#define WS_SAMP  16908288u    // 16384*4
#define WS_PART  16973824u    // 64*128*4
#define WS_PART2 17006592u    // 64*128*4
#define WS_STAT  17039360u    // 256*4

// ---------------- sq_p + new_batch ----------------
// XLA:CPU fast-math emission of sum(p*p, -1): fma(z,z, fma(x,x, y*y)).
__global__ void misc_kernel(const float* __restrict__ pos, float* __restrict__ sqp,
                            float* __restrict__ out) {
  int g = blockIdx.x * 1024 + threadIdx.x;
  if (g < NTOT) {
    float x = pos[g * 3 + 0], y = pos[g * 3 + 1], z = pos[g * 3 + 2];
    sqp[g] = fmaf(z, z, fmaf(x, x, __fmul_rn(y, y)));
  }
  if (g < MTOT) out[NEWB_OFF + g] = (float)(g >> 12);
}

// ---------------- h_pre = x @ W  (+b) ----------------
__global__ __launch_bounds__(256) void matmul_kernel(const float* __restrict__ x,
                                                     const float* __restrict__ W,
                                                     const float* __restrict__ bias,
                                                     float* __restrict__ h) {
  __shared__ float xs[16][64];
  const int tid = threadIdx.x;
  const int rowbase = blockIdx.x * 16;
  for (int i = tid; i < 16 * 64; i += 256) xs[i >> 6][i & 63] = x[rowbase * 64 + i];
  __syncthreads();
  const int col = tid & 127;
  const int rs = (tid >> 7) * 8;
  float acc[8] = {0.f, 0.f, 0.f, 0.f, 0.f, 0.f, 0.f, 0.f};
  for (int k = 0; k < 64; ++k) {
    float wv = W[k * 128 + col];
#pragma unroll
    for (int r = 0; r < 8; ++r) acc[r] = fmaf(xs[rs + r][k], wv, acc[r]);
  }
  float bb = bias[col];
#pragma unroll
  for (int r = 0; r < 8; ++r) h[(rowbase + rs + r) * 128 + col] = acc[r] + bb;
}

// ---------------- BN partial sums (deterministic tree) ----------------
__global__ __launch_bounds__(256) void stats_kernel(const float* __restrict__ h,
                                                    float* __restrict__ part,
                                                    float* __restrict__ part2) {
  const int tid = threadIdx.x;
  const int col = tid & 127;
  const int half = tid >> 7;
  const int r0 = blockIdx.x * 512;
  float s = 0.f, s2 = 0.f;
  for (int r = r0 + half; r < r0 + 512; r += 2) {
    float v = h[r * 128 + col];
    s += v;
    s2 = fmaf(v, v, s2);
  }
  __shared__ float ps[2][128], ps2[2][128];
  ps[half][col] = s;
  ps2[half][col] = s2;
  __syncthreads();
  if (half == 0) {
    part[blockIdx.x * 128 + col] = ps[0][col] + ps[1][col];
    part2[blockIdx.x * 128 + col] = ps2[0][col] + ps2[1][col];
  }
}

__global__ void finalize_kernel(const float* __restrict__ part,
                                const float* __restrict__ part2,
                                float* __restrict__ stat) {
  int col = threadIdx.x;  // 128 threads
  float s = 0.f, s2 = 0.f;
  for (int i = 0; i < 64; ++i) {
    s += part[i * 128 + col];
    s2 += part2[i * 128 + col];
  }
  float mean = s / 32768.0f;
  float var = s2 / 32768.0f - mean * mean;
  float invstd = 1.0f / sqrtf(var + 1e-5f);
  stat[col] = mean;
  stat[128 + col] = invstd;
}

// ---------------- BN apply + exact GELU (in place on h) ----------------
__global__ __launch_bounds__(256) void bngelu_kernel(float* __restrict__ h,
                                                     const float* __restrict__ stat,
                                                     const float* __restrict__ gamma,
                                                     const float* __restrict__ beta) {
  int base = blockIdx.x * 2048 + threadIdx.x;
#pragma unroll
  for (int t = 0; t < 8; ++t) {
    int g = base + t * 256;
    int col = g & 127;
    float v = h[g];
    float z = (v - stat[col]) * stat[128 + col];
    z = z * gamma[col] + beta[col];
    float ge = 0.5f * z * (1.0f + erff(z * 0.70710678118654752440f));
    h[g] = ge;
  }
}

// ---------------- deterministic FPS, one block per cloud ----------------
// r5 plumbing, but the per-thread point cache is 64 NAMED SCALARS (not
// arrays): r5-r7 showed the compiler leaves float[16] arrays in scratch
// (VGPR_Count=56 < 64 floats), making each of the 4095 serial steps
// ~2000 cycles of L1/scratch traffic. Named scalars are SSA values ->
// guaranteed VGPR residency under the (512,2) cap of 256.
#define FPS_DECL(i) float px##i, py##i, pz##i, dd##i;
#define FPS_LOAD(i)                    \
  {                                    \
    int n = tid + (i) * 512;           \
    px##i = p[n * 3 + 0];              \
    py##i = p[n * 3 + 1];              \
    pz##i = p[n * 3 + 2];              \
    dd##i = INFINITY;                  \
  }
#define FPS_DIST(i)                                                              \
  {                                                                              \
    float dx = __fsub_rn(px##i, lx), dy = __fsub_rn(py##i, ly),                  \
          dz = __fsub_rn(pz##i, lz);                                             \
    float d = fmaf(dz, dz, fmaf(dx, dx, __fmul_rn(dy, dy)));                     \
    float nd = fminf(dd##i, d);                                                  \
    dd##i = nd;                                                                  \
    unsigned long long key =                                                     \
        ((unsigned long long)__float_as_uint(nd) << 32) |                        \
        (unsigned int)(ntid - (i) * 512u);                                       \
    bk = (key > bk) ? key : bk;                                                  \
  }
#define FPS_SELW(i)                                  \
  if (jw == (i)) { ox = px##i; oy = py##i; oz = pz##i; }

__global__ __launch_bounds__(512, 2) void fps_kernel(const float* __restrict__ pos,
                                                     int* __restrict__ samp,
                                                     float* __restrict__ out) {
  const int b = blockIdx.x;
  const int tid = threadIdx.x;
  const float* p = pos + b * NPER * 3;
  __shared__ float lastpos[3];
  __shared__ unsigned long long slot[2];
  FPS_DECL(0) FPS_DECL(1) FPS_DECL(2) FPS_DECL(3)
  FPS_DECL(4) FPS_DECL(5) FPS_DECL(6) FPS_DECL(7)
  FPS_DECL(8) FPS_DECL(9) FPS_DECL(10) FPS_DECL(11)
  FPS_DECL(12) FPS_DECL(13) FPS_DECL(14) FPS_DECL(15)
  FPS_LOAD(0) FPS_LOAD(1) FPS_LOAD(2) FPS_LOAD(3)
  FPS_LOAD(4) FPS_LOAD(5) FPS_LOAD(6) FPS_LOAD(7)
  FPS_LOAD(8) FPS_LOAD(9) FPS_LOAD(10) FPS_LOAD(11)
  FPS_LOAD(12) FPS_LOAD(13) FPS_LOAD(14) FPS_LOAD(15)
  const unsigned int ntid = ~(unsigned int)tid;
  if (tid == 0) {
    slot[0] = 0ull;
    slot[1] = 0ull;
    lastpos[0] = px0;
    lastpos[1] = py0;
    lastpos[2] = pz0;
    samp[b * MPER] = 0;
    out[NEWPOS_OFF + (b * MPER) * 3 + 0] = px0;
    out[NEWPOS_OFF + (b * MPER) * 3 + 1] = py0;
    out[NEWPOS_OFF + (b * MPER) * 3 + 2] = pz0;
  }
  __syncthreads();
  for (int s = 1; s < MPER; ++s) {
    const float lx = lastpos[0], ly = lastpos[1], lz = lastpos[2];
    unsigned long long bk = 0ull;
    FPS_DIST(0) FPS_DIST(1) FPS_DIST(2) FPS_DIST(3)
    FPS_DIST(4) FPS_DIST(5) FPS_DIST(6) FPS_DIST(7)
    FPS_DIST(8) FPS_DIST(9) FPS_DIST(10) FPS_DIST(11)
    FPS_DIST(12) FPS_DIST(13) FPS_DIST(14) FPS_DIST(15)
#pragma unroll
    for (int off = 1; off < 64; off <<= 1) {
      unsigned long long o = __shfl_xor(bk, off, 64);
      bk = (o > bk) ? o : bk;
    }
    if ((tid & 63) == 0) atomicMax(&slot[s & 1], bk);
    __syncthreads();
    unsigned long long w = slot[s & 1];
    int widx = (int)(~(unsigned int)(w & 0xFFFFFFFFull));
    if (tid == 0) slot[(s & 1) ^ 1] = 0ull;
    if (tid == (widx & 511)) {
      const int jw = widx >> 9;
      float ox = px0, oy = py0, oz = pz0;
      FPS_SELW(1) FPS_SELW(2) FPS_SELW(3) FPS_SELW(4)
      FPS_SELW(5) FPS_SELW(6) FPS_SELW(7) FPS_SELW(8)
      FPS_SELW(9) FPS_SELW(10) FPS_SELW(11) FPS_SELW(12)
      FPS_SELW(13) FPS_SELW(14) FPS_SELW(15)
      lastpos[0] = ox;
      lastpos[1] = oy;
      lastpos[2] = oz;
      samp[b * MPER + s] = widx;
      out[NEWPOS_OFF + (b * MPER + s) * 3 + 0] = ox;
      out[NEWPOS_OFF + (b * MPER + s) * 3 + 1] = oy;
      out[NEWPOS_OFF + (b * MPER + s) * 3 + 2] = oz;
    }
    __syncthreads();
  }
}

// ---------------- kNN: Eigen-style ascending fma dot, expand-formula d2 ----------------
__global__ __launch_bounds__(256) void knn_kernel(const float* __restrict__ pos,
                                                  const float* __restrict__ sqp,
                                                  const int* __restrict__ samp,
                                                  const float* __restrict__ h,
                                                  float* __restrict__ out) {
  const int q = blockIdx.x;
  const int b = q >> 12;
  const int tid = threadIdx.x;
  const int gbase = b * NPER;
  __shared__ float dist[NPER];  // 32 KB
  __shared__ unsigned long long slot[2];
  __shared__ int nbr[16];
  const int sidx = samp[q];
  const float qx = pos[(gbase + sidx) * 3 + 0];
  const float qy = pos[(gbase + sidx) * 3 + 1];
  const float qz = pos[(gbase + sidx) * 3 + 2];
  const float sqq = sqp[gbase + sidx];
  if (tid == 0) {
    slot[0] = ~0ull;
    slot[1] = ~0ull;
  }
  unsigned long long lkey = ~0ull;
  for (int i = 0; i < 32; ++i) {
    int n = tid + i * 256;
    int g = gbase + n;
    // Eigen gebp: fma(q2,p2, fma(q1,p1, rn(q0*p0)))
    float dot = fmaf(qz, pos[g * 3 + 2],
                     fmaf(qy, pos[g * 3 + 1], __fmul_rn(qx, pos[g * 3 + 0])));
    // (sq_q + sq_p) - 2*dot, each op rounded
    float d2 = __fsub_rn(__fadd_rn(sqq, sqp[g]), __fmul_rn(2.0f, dot));
    dist[n] = d2;
    unsigned int ub = __float_as_uint(d2);
    ub = (ub & 0x80000000u) ? ~ub : (ub | 0x80000000u);  // monotone float->uint
    unsigned long long key = ((unsigned long long)ub << 32) | (unsigned int)n;
    lkey = (key < lkey) ? key : lkey;
  }
  __syncthreads();
  for (int r = 0; r < 16; ++r) {
    unsigned long long wk = lkey;
#pragma unroll
    for (int off = 1; off < 64; off <<= 1) {
      unsigned long long o = __shfl_xor(wk, off, 64);
      wk = (o < wk) ? o : wk;
    }
    if ((tid & 63) == 0) atomicMin(&slot[r & 1], wk);
    __syncthreads();
    unsigned long long w = slot[r & 1];
    int n = (int)(unsigned int)(w & 0xFFFFFFFFull);
    if (tid == 0) {
      nbr[r] = n;
      slot[(r & 1) ^ 1] = ~0ull;
    }
    if (tid == (n & 255)) {  // owner removes it and refreshes its local min
      dist[n] = INFINITY;
      lkey = ~0ull;
      for (int i = 0; i < 32; ++i) {
        int nn = tid + i * 256;
        unsigned int ub = __float_as_uint(dist[nn]);
        ub = (ub & 0x80000000u) ? ~ub : (ub | 0x80000000u);
        unsigned long long kk = ((unsigned long long)ub << 32) | (unsigned int)nn;
        lkey = (kk < lkey) ? kk : lkey;
      }
    }
    __syncthreads();
  }
  if (tid < COUT) {
    float mx = -INFINITY;
#pragma unroll
    for (int r = 0; r < 16; ++r) mx = fmaxf(mx, h[(gbase + nbr[r]) * 128 + tid]);
    out[q * 128 + tid] = mx;
  }
}

extern "C" void kernel_launch(void* const* d_in, const int* in_sizes, int n_in,
                              void* d_out, int out_size, void* d_ws, size_t ws_size,
                              hipStream_t stream) {
  (void)in_sizes; (void)n_in; (void)out_size; (void)ws_size;
  const float* x     = (const float*)d_in[0];
  const float* pos   = (const float*)d_in[1];
  const float* W     = (const float*)d_in[3];
  const float* bias  = (const float*)d_in[4];
  const float* gamma = (const float*)d_in[5];
  const float* beta  = (const float*)d_in[6];
  float* out = (float*)d_out;
  char* ws = (char*)d_ws;
  float* h     = (float*)(ws + WS_H);
  float* sqp   = (float*)(ws + WS_SQP);
  int*   samp  = (int*)(ws + WS_SAMP);
  float* part  = (float*)(ws + WS_PART);
  float* part2 = (float*)(ws + WS_PART2);
  float* stat  = (float*)(ws + WS_STAT);

  misc_kernel<<<dim3(32), dim3(1024), 0, stream>>>(pos, sqp, out);
  matmul_kernel<<<dim3(2048), dim3(256), 0, stream>>>(x, W, bias, h);
  stats_kernel<<<dim3(64), dim3(256), 0, stream>>>(h, part, part2);
  finalize_kernel<<<dim3(1), dim3(128), 0, stream>>>(part, part2, stat);
  bngelu_kernel<<<dim3(2048), dim3(256), 0, stream>>>(h, stat, gamma, beta);
  fps_kernel<<<dim3(NB), dim3(512), 0, stream>>>(pos, samp, out);
  knn_kernel<<<dim3(MTOT), dim3(256), 0, stream>>>(pos, sqp, samp, h, out);
}

// Round 9
// 5407.684 us; speedup vs baseline: 1.0632x; 1.0632x over previous
//
#include <hip/hip_runtime.h>
#include <math.h>

#define NB    4
#define NPER  8192
#define MPER  4096
#define NTOT  32768
#define MTOT  16384
#define COUT  128

// d_out layout (floats): new_x [16384*128] | new_pos [16384*3] | new_batch [16384]
#define NEWPOS_OFF 2097152
#define NEWB_OFF   2146304

// workspace layout (bytes); ~17 MB
#define WS_H     0u           // 32768*128*4 = 16777216
#define WS_SQP   16777216u    // 32768*4
#define WS_SAMP  16908288u    // 16384*4
#define WS_PART  16973824u    // 64*128*4
#define WS_PART2 17006592u    // 64*128*4
#define WS_STAT  17039360u    // 256*4

// ---------------- sq_p + new_batch ----------------
// XLA:CPU fast-math emission of sum(p*p, -1): fma(z,z, fma(x,x, y*y)).
__global__ void misc_kernel(const float* __restrict__ pos, float* __restrict__ sqp,
                            float* __restrict__ out) {
  int g = blockIdx.x * 1024 + threadIdx.x;
  if (g < NTOT) {
    float x = pos[g * 3 + 0], y = pos[g * 3 + 1], z = pos[g * 3 + 2];
    sqp[g] = fmaf(z, z, fmaf(x, x, __fmul_rn(y, y)));
  }
  if (g < MTOT) out[NEWB_OFF + g] = (float)(g >> 12);
}

// ---------------- h_pre = x @ W  (+b) ----------------
__global__ __launch_bounds__(256) void matmul_kernel(const float* __restrict__ x,
                                                     const float* __restrict__ W,
                                                     const float* __restrict__ bias,
                                                     float* __restrict__ h) {
  __shared__ float xs[16][64];
  const int tid = threadIdx.x;
  const int rowbase = blockIdx.x * 16;
  for (int i = tid; i < 16 * 64; i += 256) xs[i >> 6][i & 63] = x[rowbase * 64 + i];
  __syncthreads();
  const int col = tid & 127;
  const int rs = (tid >> 7) * 8;
  float acc[8] = {0.f, 0.f, 0.f, 0.f, 0.f, 0.f, 0.f, 0.f};
  for (int k = 0; k < 64; ++k) {
    float wv = W[k * 128 + col];
#pragma unroll
    for (int r = 0; r < 8; ++r) acc[r] = fmaf(xs[rs + r][k], wv, acc[r]);
  }
  float bb = bias[col];
#pragma unroll
  for (int r = 0; r < 8; ++r) h[(rowbase + rs + r) * 128 + col] = acc[r] + bb;
}

// ---------------- BN partial sums (deterministic tree) ----------------
__global__ __launch_bounds__(256) void stats_kernel(const float* __restrict__ h,
                                                    float* __restrict__ part,
                                                    float* __restrict__ part2) {
  const int tid = threadIdx.x;
  const int col = tid & 127;
  const int half = tid >> 7;
  const int r0 = blockIdx.x * 512;
  float s = 0.f, s2 = 0.f;
  for (int r = r0 + half; r < r0 + 512; r += 2) {
    float v = h[r * 128 + col];
    s += v;
    s2 = fmaf(v, v, s2);
  }
  __shared__ float ps[2][128], ps2[2][128];
  ps[half][col] = s;
  ps2[half][col] = s2;
  __syncthreads();
  if (half == 0) {
    part[blockIdx.x * 128 + col] = ps[0][col] + ps[1][col];
    part2[blockIdx.x * 128 + col] = ps2[0][col] + ps2[1][col];
  }
}

__global__ void finalize_kernel(const float* __restrict__ part,
                                const float* __restrict__ part2,
                                float* __restrict__ stat) {
  int col = threadIdx.x;  // 128 threads
  float s = 0.f, s2 = 0.f;
  for (int i = 0; i < 64; ++i) {
    s += part[i * 128 + col];
    s2 += part2[i * 128 + col];
  }
  float mean = s / 32768.0f;
  float var = s2 / 32768.0f - mean * mean;
  float invstd = 1.0f / sqrtf(var + 1e-5f);
  stat[col] = mean;
  stat[128 + col] = invstd;
}

// ---------------- BN apply + exact GELU (in place on h) ----------------
__global__ __launch_bounds__(256) void bngelu_kernel(float* __restrict__ h,
                                                     const float* __restrict__ stat,
                                                     const float* __restrict__ gamma,
                                                     const float* __restrict__ beta) {
  int base = blockIdx.x * 2048 + threadIdx.x;
#pragma unroll
  for (int t = 0; t < 8; ++t) {
    int g = base + t * 256;
    int col = g & 127;
    float v = h[g];
    float z = (v - stat[col]) * stat[128 + col];
    z = z * gamma[col] + beta[col];
    float ge = 0.5f * z * (1.0f + erff(z * 0.70710678118654752440f));
    h[g] = ge;
  }
}

// ---------------- deterministic FPS, one block per cloud ----------------
// r8 structure + ASM PINNING: r8 proved the compiler rematerializes the
// position loads inside the 4095-step serial loop (barrier = memory
// clobber, so hoisting isn't proven safe; VGPR_Count stayed 56). The
// empty asm with "+v" redefines each coordinate as an asm output --
// provenance is no longer the load, so it CANNOT be rematerialized and
// must stay resident in a VGPR across the whole loop.
#define FPS_DECL(i) float px##i, py##i, pz##i, dd##i;
#define FPS_LOAD(i)                    \
  {                                    \
    int n = tid + (i) * 512;           \
    px##i = p[n * 3 + 0];              \
    py##i = p[n * 3 + 1];              \
    pz##i = p[n * 3 + 2];              \
    dd##i = INFINITY;                  \
  }
#define FPS_PIN(i) \
  asm volatile("" : "+v"(px##i), "+v"(py##i), "+v"(pz##i));
#define FPS_DIST(i)                                                              \
  {                                                                              \
    float dx = __fsub_rn(px##i, lx), dy = __fsub_rn(py##i, ly),                  \
          dz = __fsub_rn(pz##i, lz);                                             \
    float d = fmaf(dz, dz, fmaf(dx, dx, __fmul_rn(dy, dy)));                     \
    float nd = fminf(dd##i, d);                                                  \
    dd##i = nd;                                                                  \
    unsigned long long key =                                                     \
        ((unsigned long long)__float_as_uint(nd) << 32) |                        \
        (unsigned int)(ntid - (i) * 512u);                                       \
    bk = (key > bk) ? key : bk;                                                  \
  }
#define FPS_SELW(i)                                  \
  if (jw == (i)) { ox = px##i; oy = py##i; oz = pz##i; }

__global__ __launch_bounds__(512, 2) void fps_kernel(const float* __restrict__ pos,
                                                     int* __restrict__ samp,
                                                     float* __restrict__ out) {
  const int b = blockIdx.x;
  const int tid = threadIdx.x;
  const float* p = pos + b * NPER * 3;
  __shared__ float lastpos[3];
  __shared__ unsigned long long slot[2];
  FPS_DECL(0) FPS_DECL(1) FPS_DECL(2) FPS_DECL(3)
  FPS_DECL(4) FPS_DECL(5) FPS_DECL(6) FPS_DECL(7)
  FPS_DECL(8) FPS_DECL(9) FPS_DECL(10) FPS_DECL(11)
  FPS_DECL(12) FPS_DECL(13) FPS_DECL(14) FPS_DECL(15)
  FPS_LOAD(0) FPS_LOAD(1) FPS_LOAD(2) FPS_LOAD(3)
  FPS_LOAD(4) FPS_LOAD(5) FPS_LOAD(6) FPS_LOAD(7)
  FPS_LOAD(8) FPS_LOAD(9) FPS_LOAD(10) FPS_LOAD(11)
  FPS_LOAD(12) FPS_LOAD(13) FPS_LOAD(14) FPS_LOAD(15)
  FPS_PIN(0) FPS_PIN(1) FPS_PIN(2) FPS_PIN(3)
  FPS_PIN(4) FPS_PIN(5) FPS_PIN(6) FPS_PIN(7)
  FPS_PIN(8) FPS_PIN(9) FPS_PIN(10) FPS_PIN(11)
  FPS_PIN(12) FPS_PIN(13) FPS_PIN(14) FPS_PIN(15)
  const unsigned int ntid = ~(unsigned int)tid;
  if (tid == 0) {
    slot[0] = 0ull;
    slot[1] = 0ull;
    lastpos[0] = px0;
    lastpos[1] = py0;
    lastpos[2] = pz0;
    samp[b * MPER] = 0;
    out[NEWPOS_OFF + (b * MPER) * 3 + 0] = px0;
    out[NEWPOS_OFF + (b * MPER) * 3 + 1] = py0;
    out[NEWPOS_OFF + (b * MPER) * 3 + 2] = pz0;
  }
  __syncthreads();
  for (int s = 1; s < MPER; ++s) {
    const float lx = lastpos[0], ly = lastpos[1], lz = lastpos[2];
    unsigned long long bk = 0ull;
    FPS_DIST(0) FPS_DIST(1) FPS_DIST(2) FPS_DIST(3)
    FPS_DIST(4) FPS_DIST(5) FPS_DIST(6) FPS_DIST(7)
    FPS_DIST(8) FPS_DIST(9) FPS_DIST(10) FPS_DIST(11)
    FPS_DIST(12) FPS_DIST(13) FPS_DIST(14) FPS_DIST(15)
#pragma unroll
    for (int off = 1; off < 64; off <<= 1) {
      unsigned long long o = __shfl_xor(bk, off, 64);
      bk = (o > bk) ? o : bk;
    }
    if ((tid & 63) == 0) atomicMax(&slot[s & 1], bk);
    __syncthreads();
    unsigned long long w = slot[s & 1];
    int widx = (int)(~(unsigned int)(w & 0xFFFFFFFFull));
    if (tid == 0) slot[(s & 1) ^ 1] = 0ull;
    if (tid == (widx & 511)) {
      const int jw = widx >> 9;
      float ox = px0, oy = py0, oz = pz0;
      FPS_SELW(1) FPS_SELW(2) FPS_SELW(3) FPS_SELW(4)
      FPS_SELW(5) FPS_SELW(6) FPS_SELW(7) FPS_SELW(8)
      FPS_SELW(9) FPS_SELW(10) FPS_SELW(11) FPS_SELW(12)
      FPS_SELW(13) FPS_SELW(14) FPS_SELW(15)
      lastpos[0] = ox;
      lastpos[1] = oy;
      lastpos[2] = oz;
      samp[b * MPER + s] = widx;
      out[NEWPOS_OFF + (b * MPER + s) * 3 + 0] = ox;
      out[NEWPOS_OFF + (b * MPER + s) * 3 + 1] = oy;
      out[NEWPOS_OFF + (b * MPER + s) * 3 + 2] = oz;
    }
    __syncthreads();
  }
}

// ---------------- kNN: Eigen-style ascending fma dot, expand-formula d2 ----------------
__global__ __launch_bounds__(256) void knn_kernel(const float* __restrict__ pos,
                                                  const float* __restrict__ sqp,
                                                  const int* __restrict__ samp,
                                                  const float* __restrict__ h,
                                                  float* __restrict__ out) {
  const int q = blockIdx.x;
  const int b = q >> 12;
  const int tid = threadIdx.x;
  const int gbase = b * NPER;
  __shared__ float dist[NPER];  // 32 KB
  __shared__ unsigned long long slot[2];
  __shared__ int nbr[16];
  const int sidx = samp[q];
  const float qx = pos[(gbase + sidx) * 3 + 0];
  const float qy = pos[(gbase + sidx) * 3 + 1];
  const float qz = pos[(gbase + sidx) * 3 + 2];
  const float sqq = sqp[gbase + sidx];
  if (tid == 0) {
    slot[0] = ~0ull;
    slot[1] = ~0ull;
  }
  unsigned long long lkey = ~0ull;
  for (int i = 0; i < 32; ++i) {
    int n = tid + i * 256;
    int g = gbase + n;
    // Eigen gebp: fma(q2,p2, fma(q1,p1, rn(q0*p0)))
    float dot = fmaf(qz, pos[g * 3 + 2],
                     fmaf(qy, pos[g * 3 + 1], __fmul_rn(qx, pos[g * 3 + 0])));
    // (sq_q + sq_p) - 2*dot, each op rounded
    float d2 = __fsub_rn(__fadd_rn(sqq, sqp[g]), __fmul_rn(2.0f, dot));
    dist[n] = d2;
    unsigned int ub = __float_as_uint(d2);
    ub = (ub & 0x80000000u) ? ~ub : (ub | 0x80000000u);  // monotone float->uint
    unsigned long long key = ((unsigned long long)ub << 32) | (unsigned int)n;
    lkey = (key < lkey) ? key : lkey;
  }
  __syncthreads();
  for (int r = 0; r < 16; ++r) {
    unsigned long long wk = lkey;
#pragma unroll
    for (int off = 1; off < 64; off <<= 1) {
      unsigned long long o = __shfl_xor(wk, off, 64);
      wk = (o < wk) ? o : wk;
    }
    if ((tid & 63) == 0) atomicMin(&slot[r & 1], wk);
    __syncthreads();
    unsigned long long w = slot[r & 1];
    int n = (int)(unsigned int)(w & 0xFFFFFFFFull);
    if (tid == 0) {
      nbr[r] = n;
      slot[(r & 1) ^ 1] = ~0ull;
    }
    if (tid == (n & 255)) {  // owner removes it and refreshes its local min
      dist[n] = INFINITY;
      lkey = ~0ull;
      for (int i = 0; i < 32; ++i) {
        int nn = tid + i * 256;
        unsigned int ub = __float_as_uint(dist[nn]);
        ub = (ub & 0x80000000u) ? ~ub : (ub | 0x80000000u);
        unsigned long long kk = ((unsigned long long)ub << 32) | (unsigned int)nn;
        lkey = (kk < lkey) ? kk : lkey;
      }
    }
    __syncthreads();
  }
  if (tid < COUT) {
    float mx = -INFINITY;
#pragma unroll
    for (int r = 0; r < 16; ++r) mx = fmaxf(mx, h[(gbase + nbr[r]) * 128 + tid]);
    out[q * 128 + tid] = mx;
  }
}

extern "C" void kernel_launch(void* const* d_in, const int* in_sizes, int n_in,
                              void* d_out, int out_size, void* d_ws, size_t ws_size,
                              hipStream_t stream) {
  (void)in_sizes; (void)n_in; (void)out_size; (void)ws_size;
  const float* x     = (const float*)d_in[0];
  const float* pos   = (const float*)d_in[1];
  const float* W     = (const float*)d_in[3];
  const float* bias  = (const float*)d_in[4];
  const float* gamma = (const float*)d_in[5];
  const float* beta  = (const float*)d_in[6];
  float* out = (float*)d_out;
  char* ws = (char*)d_ws;
  float* h     = (float*)(ws + WS_H);
  float* sqp   = (float*)(ws + WS_SQP);
  int*   samp  = (int*)(ws + WS_SAMP);
  float* part  = (float*)(ws + WS_PART);
  float* part2 = (float*)(ws + WS_PART2);
  float* stat  = (float*)(ws + WS_STAT);

  misc_kernel<<<dim3(32), dim3(1024), 0, stream>>>(pos, sqp, out);
  matmul_kernel<<<dim3(2048), dim3(256), 0, stream>>>(x, W, bias, h);
  stats_kernel<<<dim3(64), dim3(256), 0, stream>>>(h, part, part2);
  finalize_kernel<<<dim3(1), dim3(128), 0, stream>>>(part, part2, stat);
  bngelu_kernel<<<dim3(2048), dim3(256), 0, stream>>>(h, stat, gamma, beta);
  fps_kernel<<<dim3(NB), dim3(512), 0, stream>>>(pos, samp, out);
  knn_kernel<<<dim3(MTOT), dim3(256), 0, stream>>>(pos, sqp, samp, h, out);
}

// Round 10
// 5336.923 us; speedup vs baseline: 1.0773x; 1.0133x over previous
//
#include <hip/hip_runtime.h>
#include <math.h>

#define NB    4
#define NPER  8192
#define MPER  4096
#define NTOT  32768
#define MTOT  16384
#define COUT  128

// d_out layout (floats): new_x [16384*128] | new_pos [16384*3] | new_batch [16384]
#define NEWPOS_OFF 2097152
#define NEWB_OFF   2146304

// workspace layout (bytes); ~17 MB
#define WS_H     0u           // 32768*128*4 = 16777216
#define WS_SQP   16777216u    // 32768*4
#define WS_SAMP  16908288u    // 16384*4
#define WS_PART  16973824u    // 64*128*4
#define WS_PART2 17006592u    // 64*128*4
#define WS_STAT  17039360u    // 256*4

// ---------------- sq_p + new_batch ----------------
// XLA:CPU fast-math emission of sum(p*p, -1): fma(z,z, fma(x,x, y*y)).
__global__ void misc_kernel(const float* __restrict__ pos, float* __restrict__ sqp,
                            float* __restrict__ out) {
  int g = blockIdx.x * 1024 + threadIdx.x;
  if (g < NTOT) {
    float x = pos[g * 3 + 0], y = pos[g * 3 + 1], z = pos[g * 3 + 2];
    sqp[g] = fmaf(z, z, fmaf(x, x, __fmul_rn(y, y)));
  }
  if (g < MTOT) out[NEWB_OFF + g] = (float)(g >> 12);
}

// ---------------- h_pre = x @ W  (+b) ----------------
__global__ __launch_bounds__(256) void matmul_kernel(const float* __restrict__ x,
                                                     const float* __restrict__ W,
                                                     const float* __restrict__ bias,
                                                     float* __restrict__ h) {
  __shared__ float xs[16][64];
  const int tid = threadIdx.x;
  const int rowbase = blockIdx.x * 16;
  for (int i = tid; i < 16 * 64; i += 256) xs[i >> 6][i & 63] = x[rowbase * 64 + i];
  __syncthreads();
  const int col = tid & 127;
  const int rs = (tid >> 7) * 8;
  float acc[8] = {0.f, 0.f, 0.f, 0.f, 0.f, 0.f, 0.f, 0.f};
  for (int k = 0; k < 64; ++k) {
    float wv = W[k * 128 + col];
#pragma unroll
    for (int r = 0; r < 8; ++r) acc[r] = fmaf(xs[rs + r][k], wv, acc[r]);
  }
  float bb = bias[col];
#pragma unroll
  for (int r = 0; r < 8; ++r) h[(rowbase + rs + r) * 128 + col] = acc[r] + bb;
}

// ---------------- BN partial sums (deterministic tree) ----------------
__global__ __launch_bounds__(256) void stats_kernel(const float* __restrict__ h,
                                                    float* __restrict__ part,
                                                    float* __restrict__ part2) {
  const int tid = threadIdx.x;
  const int col = tid & 127;
  const int half = tid >> 7;
  const int r0 = blockIdx.x * 512;
  float s = 0.f, s2 = 0.f;
  for (int r = r0 + half; r < r0 + 512; r += 2) {
    float v = h[r * 128 + col];
    s += v;
    s2 = fmaf(v, v, s2);
  }
  __shared__ float ps[2][128], ps2[2][128];
  ps[half][col] = s;
  ps2[half][col] = s2;
  __syncthreads();
  if (half == 0) {
    part[blockIdx.x * 128 + col] = ps[0][col] + ps[1][col];
    part2[blockIdx.x * 128 + col] = ps2[0][col] + ps2[1][col];
  }
}

__global__ void finalize_kernel(const float* __restrict__ part,
                                const float* __restrict__ part2,
                                float* __restrict__ stat) {
  int col = threadIdx.x;  // 128 threads
  float s = 0.f, s2 = 0.f;
  for (int i = 0; i < 64; ++i) {
    s += part[i * 128 + col];
    s2 += part2[i * 128 + col];
  }
  float mean = s / 32768.0f;
  float var = s2 / 32768.0f - mean * mean;
  float invstd = 1.0f / sqrtf(var + 1e-5f);
  stat[col] = mean;
  stat[128 + col] = invstd;
}

// ---------------- BN apply + exact GELU (in place on h) ----------------
__global__ __launch_bounds__(256) void bngelu_kernel(float* __restrict__ h,
                                                     const float* __restrict__ stat,
                                                     const float* __restrict__ gamma,
                                                     const float* __restrict__ beta) {
  int base = blockIdx.x * 2048 + threadIdx.x;
#pragma unroll
  for (int t = 0; t < 8; ++t) {
    int g = base + t * 256;
    int col = g & 127;
    float v = h[g];
    float z = (v - stat[col]) * stat[128 + col];
    z = z * gamma[col] + beta[col];
    float ge = 0.5f * z * (1.0f + erff(z * 0.70710678118654752440f));
    h[g] = ge;
  }
}

// ---------------- deterministic FPS, one block per cloud ----------------
// 1024 threads x 8 points/thread: r7-r9 proved the register allocator
// will only keep ~52 VGPRs live across this barrier loop (16-pt working
// set spilled to scratch -> ~1100 cyc/step of reload traffic). With 8
// points/thread the whole cache (24 pos + 8 dd floats) fits the budget
// the RA actually allocates. Same total VALU work, zero spill.
#define FPS_DECL(i) float px##i, py##i, pz##i, dd##i;
#define FPS_LOAD(i)                    \
  {                                    \
    int n = tid + (i) * 1024;          \
    px##i = p[n * 3 + 0];              \
    py##i = p[n * 3 + 1];              \
    pz##i = p[n * 3 + 2];              \
    dd##i = INFINITY;                  \
  }
#define FPS_PIN(i) \
  asm volatile("" : "+v"(px##i), "+v"(py##i), "+v"(pz##i));
#define FPS_DIST(i)                                                              \
  {                                                                              \
    float dx = __fsub_rn(px##i, lx), dy = __fsub_rn(py##i, ly),                  \
          dz = __fsub_rn(pz##i, lz);                                             \
    float d = fmaf(dz, dz, fmaf(dx, dx, __fmul_rn(dy, dy)));                     \
    float nd = fminf(dd##i, d);                                                  \
    dd##i = nd;                                                                  \
    unsigned long long key =                                                     \
        ((unsigned long long)__float_as_uint(nd) << 32) |                        \
        (unsigned int)(ntid - (i) * 1024u);                                      \
    bk = (key > bk) ? key : bk;                                                  \
  }
#define FPS_SELW(i)                                  \
  if (jw == (i)) { ox = px##i; oy = py##i; oz = pz##i; }

__global__ __launch_bounds__(1024, 4) void fps_kernel(const float* __restrict__ pos,
                                                      int* __restrict__ samp,
                                                      float* __restrict__ out) {
  const int b = blockIdx.x;
  const int tid = threadIdx.x;
  const float* p = pos + b * NPER * 3;
  __shared__ float lastpos[3];
  __shared__ unsigned long long slot[2];
  FPS_DECL(0) FPS_DECL(1) FPS_DECL(2) FPS_DECL(3)
  FPS_DECL(4) FPS_DECL(5) FPS_DECL(6) FPS_DECL(7)
  FPS_LOAD(0) FPS_LOAD(1) FPS_LOAD(2) FPS_LOAD(3)
  FPS_LOAD(4) FPS_LOAD(5) FPS_LOAD(6) FPS_LOAD(7)
  FPS_PIN(0) FPS_PIN(1) FPS_PIN(2) FPS_PIN(3)
  FPS_PIN(4) FPS_PIN(5) FPS_PIN(6) FPS_PIN(7)
  const unsigned int ntid = ~(unsigned int)tid;
  if (tid == 0) {
    slot[0] = 0ull;
    slot[1] = 0ull;
    lastpos[0] = px0;
    lastpos[1] = py0;
    lastpos[2] = pz0;
    samp[b * MPER] = 0;
    out[NEWPOS_OFF + (b * MPER) * 3 + 0] = px0;
    out[NEWPOS_OFF + (b * MPER) * 3 + 1] = py0;
    out[NEWPOS_OFF + (b * MPER) * 3 + 2] = pz0;
  }
  __syncthreads();
  for (int s = 1; s < MPER; ++s) {
    const float lx = lastpos[0], ly = lastpos[1], lz = lastpos[2];
    unsigned long long bk = 0ull;
    FPS_DIST(0) FPS_DIST(1) FPS_DIST(2) FPS_DIST(3)
    FPS_DIST(4) FPS_DIST(5) FPS_DIST(6) FPS_DIST(7)
#pragma unroll
    for (int off = 1; off < 64; off <<= 1) {
      unsigned long long o = __shfl_xor(bk, off, 64);
      bk = (o > bk) ? o : bk;
    }
    if ((tid & 63) == 0) atomicMax(&slot[s & 1], bk);
    __syncthreads();
    unsigned long long w = slot[s & 1];
    int widx = (int)(~(unsigned int)(w & 0xFFFFFFFFull));
    if (tid == 0) slot[(s & 1) ^ 1] = 0ull;
    if (tid == (widx & 1023)) {
      const int jw = widx >> 10;
      float ox = px0, oy = py0, oz = pz0;
      FPS_SELW(1) FPS_SELW(2) FPS_SELW(3)
      FPS_SELW(4) FPS_SELW(5) FPS_SELW(6) FPS_SELW(7)
      lastpos[0] = ox;
      lastpos[1] = oy;
      lastpos[2] = oz;
      samp[b * MPER + s] = widx;
      out[NEWPOS_OFF + (b * MPER + s) * 3 + 0] = ox;
      out[NEWPOS_OFF + (b * MPER + s) * 3 + 1] = oy;
      out[NEWPOS_OFF + (b * MPER + s) * 3 + 2] = oz;
    }
    __syncthreads();
  }
}

// ---------------- kNN: Eigen-style ascending fma dot, expand-formula d2 ----------------
__global__ __launch_bounds__(256) void knn_kernel(const float* __restrict__ pos,
                                                  const float* __restrict__ sqp,
                                                  const int* __restrict__ samp,
                                                  const float* __restrict__ h,
                                                  float* __restrict__ out) {
  const int q = blockIdx.x;
  const int b = q >> 12;
  const int tid = threadIdx.x;
  const int gbase = b * NPER;
  __shared__ float dist[NPER];  // 32 KB
  __shared__ unsigned long long slot[2];
  __shared__ int nbr[16];
  const int sidx = samp[q];
  const float qx = pos[(gbase + sidx) * 3 + 0];
  const float qy = pos[(gbase + sidx) * 3 + 1];
  const float qz = pos[(gbase + sidx) * 3 + 2];
  const float sqq = sqp[gbase + sidx];
  if (tid == 0) {
    slot[0] = ~0ull;
    slot[1] = ~0ull;
  }
  unsigned long long lkey = ~0ull;
  for (int i = 0; i < 32; ++i) {
    int n = tid + i * 256;
    int g = gbase + n;
    // Eigen gebp: fma(q2,p2, fma(q1,p1, rn(q0*p0)))
    float dot = fmaf(qz, pos[g * 3 + 2],
                     fmaf(qy, pos[g * 3 + 1], __fmul_rn(qx, pos[g * 3 + 0])));
    // (sq_q + sq_p) - 2*dot, each op rounded
    float d2 = __fsub_rn(__fadd_rn(sqq, sqp[g]), __fmul_rn(2.0f, dot));
    dist[n] = d2;
    unsigned int ub = __float_as_uint(d2);
    ub = (ub & 0x80000000u) ? ~ub : (ub | 0x80000000u);  // monotone float->uint
    unsigned long long key = ((unsigned long long)ub << 32) | (unsigned int)n;
    lkey = (key < lkey) ? key : lkey;
  }
  __syncthreads();
  for (int r = 0; r < 16; ++r) {
    unsigned long long wk = lkey;
#pragma unroll
    for (int off = 1; off < 64; off <<= 1) {
      unsigned long long o = __shfl_xor(wk, off, 64);
      wk = (o < wk) ? o : wk;
    }
    if ((tid & 63) == 0) atomicMin(&slot[r & 1], wk);
    __syncthreads();
    unsigned long long w = slot[r & 1];
    int n = (int)(unsigned int)(w & 0xFFFFFFFFull);
    if (tid == 0) {
      nbr[r] = n;
      slot[(r & 1) ^ 1] = ~0ull;
    }
    if (tid == (n & 255)) {  // owner removes it and refreshes its local min
      dist[n] = INFINITY;
      lkey = ~0ull;
      for (int i = 0; i < 32; ++i) {
        int nn = tid + i * 256;
        unsigned int ub = __float_as_uint(dist[nn]);
        ub = (ub & 0x80000000u) ? ~ub : (ub | 0x80000000u);
        unsigned long long kk = ((unsigned long long)ub << 32) | (unsigned int)nn;
        lkey = (kk < lkey) ? kk : lkey;
      }
    }
    __syncthreads();
  }
  if (tid < COUT) {
    float mx = -INFINITY;
#pragma unroll
    for (int r = 0; r < 16; ++r) mx = fmaxf(mx, h[(gbase + nbr[r]) * 128 + tid]);
    out[q * 128 + tid] = mx;
  }
}

extern "C" void kernel_launch(void* const* d_in, const int* in_sizes, int n_in,
                              void* d_out, int out_size, void* d_ws, size_t ws_size,
                              hipStream_t stream) {
  (void)in_sizes; (void)n_in; (void)out_size; (void)ws_size;
  const float* x     = (const float*)d_in[0];
  const float* pos   = (const float*)d_in[1];
  const float* W     = (const float*)d_in[3];
  const float* bias  = (const float*)d_in[4];
  const float* gamma = (const float*)d_in[5];
  const float* beta  = (const float*)d_in[6];
  float* out = (float*)d_out;
  char* ws = (char*)d_ws;
  float* h     = (float*)(ws + WS_H);
  float* sqp   = (float*)(ws + WS_SQP);
  int*   samp  = (int*)(ws + WS_SAMP);
  float* part  = (float*)(ws + WS_PART);
  float* part2 = (float*)(ws + WS_PART2);
  float* stat  = (float*)(ws + WS_STAT);

  misc_kernel<<<dim3(32), dim3(1024), 0, stream>>>(pos, sqp, out);
  matmul_kernel<<<dim3(2048), dim3(256), 0, stream>>>(x, W, bias, h);
  stats_kernel<<<dim3(64), dim3(256), 0, stream>>>(h, part, part2);
  finalize_kernel<<<dim3(1), dim3(128), 0, stream>>>(part, part2, stat);
  bngelu_kernel<<<dim3(2048), dim3(256), 0, stream>>>(h, stat, gamma, beta);
  fps_kernel<<<dim3(NB), dim3(1024), 0, stream>>>(pos, samp, out);
  knn_kernel<<<dim3(MTOT), dim3(256), 0, stream>>>(pos, sqp, samp, h, out);
}

// Round 11
// 5233.101 us; speedup vs baseline: 1.0987x; 1.0198x over previous
//
#include <hip/hip_runtime.h>
#include <math.h>

#define NB    4
#define NPER  8192
#define MPER  4096
#define NTOT  32768
#define MTOT  16384
#define COUT  128

// d_out layout (floats): new_x [16384*128] | new_pos [16384*3] | new_batch [16384]
#define NEWPOS_OFF 2097152
#define NEWB_OFF   2146304

// workspace layout (bytes); ~17 MB
#define WS_H     0u           // 32768*128*4 = 16777216
#define WS_SQP   16777216u    // 32768*4
#define WS_SAMP  16908288u    // 16384*4
#define WS_PART  16973824u    // 64*128*4
#define WS_PART2 17006592u    // 64*128*4
#define WS_STAT  17039360u    // 256*4

// ---------------- sq_p + new_batch ----------------
// XLA:CPU fast-math emission of sum(p*p, -1): fma(z,z, fma(x,x, y*y)).
__global__ void misc_kernel(const float* __restrict__ pos, float* __restrict__ sqp,
                            float* __restrict__ out) {
  int g = blockIdx.x * 1024 + threadIdx.x;
  if (g < NTOT) {
    float x = pos[g * 3 + 0], y = pos[g * 3 + 1], z = pos[g * 3 + 2];
    sqp[g] = fmaf(z, z, fmaf(x, x, __fmul_rn(y, y)));
  }
  if (g < MTOT) out[NEWB_OFF + g] = (float)(g >> 12);
}

// ---------------- h_pre = x @ W  (+b) ----------------
__global__ __launch_bounds__(256) void matmul_kernel(const float* __restrict__ x,
                                                     const float* __restrict__ W,
                                                     const float* __restrict__ bias,
                                                     float* __restrict__ h) {
  __shared__ float xs[16][64];
  const int tid = threadIdx.x;
  const int rowbase = blockIdx.x * 16;
  for (int i = tid; i < 16 * 64; i += 256) xs[i >> 6][i & 63] = x[rowbase * 64 + i];
  __syncthreads();
  const int col = tid & 127;
  const int rs = (tid >> 7) * 8;
  float acc[8] = {0.f, 0.f, 0.f, 0.f, 0.f, 0.f, 0.f, 0.f};
  for (int k = 0; k < 64; ++k) {
    float wv = W[k * 128 + col];
#pragma unroll
    for (int r = 0; r < 8; ++r) acc[r] = fmaf(xs[rs + r][k], wv, acc[r]);
  }
  float bb = bias[col];
#pragma unroll
  for (int r = 0; r < 8; ++r) h[(rowbase + rs + r) * 128 + col] = acc[r] + bb;
}

// ---------------- BN partial sums (deterministic tree) ----------------
__global__ __launch_bounds__(256) void stats_kernel(const float* __restrict__ h,
                                                    float* __restrict__ part,
                                                    float* __restrict__ part2) {
  const int tid = threadIdx.x;
  const int col = tid & 127;
  const int half = tid >> 7;
  const int r0 = blockIdx.x * 512;
  float s = 0.f, s2 = 0.f;
  for (int r = r0 + half; r < r0 + 512; r += 2) {
    float v = h[r * 128 + col];
    s += v;
    s2 = fmaf(v, v, s2);
  }
  __shared__ float ps[2][128], ps2[2][128];
  ps[half][col] = s;
  ps2[half][col] = s2;
  __syncthreads();
  if (half == 0) {
    part[blockIdx.x * 128 + col] = ps[0][col] + ps[1][col];
    part2[blockIdx.x * 128 + col] = ps2[0][col] + ps2[1][col];
  }
}

__global__ void finalize_kernel(const float* __restrict__ part,
                                const float* __restrict__ part2,
                                float* __restrict__ stat) {
  int col = threadIdx.x;  // 128 threads
  float s = 0.f, s2 = 0.f;
  for (int i = 0; i < 64; ++i) {
    s += part[i * 128 + col];
    s2 += part2[i * 128 + col];
  }
  float mean = s / 32768.0f;
  float var = s2 / 32768.0f - mean * mean;
  float invstd = 1.0f / sqrtf(var + 1e-5f);
  stat[col] = mean;
  stat[128 + col] = invstd;
}

// ---------------- BN apply + exact GELU (in place on h) ----------------
__global__ __launch_bounds__(256) void bngelu_kernel(float* __restrict__ h,
                                                     const float* __restrict__ stat,
                                                     const float* __restrict__ gamma,
                                                     const float* __restrict__ beta) {
  int base = blockIdx.x * 2048 + threadIdx.x;
#pragma unroll
  for (int t = 0; t < 8; ++t) {
    int g = base + t * 256;
    int col = g & 127;
    float v = h[g];
    float z = (v - stat[col]) * stat[128 + col];
    z = z * gamma[col] + beta[col];
    float ge = 0.5f * z * (1.0f + erff(z * 0.70710678118654752440f));
    h[g] = ge;
  }
}

// ---------------- deterministic FPS, one block per cloud ----------------
// r10 structure + amdgpu_waves_per_eu(4,4): r10's counters (VGPR=32,
// Occupancy doubled) proved the RA spills the point cache ON PURPOSE to
// fit 2 blocks/CU (8 waves/SIMD). launch_bounds' 2nd arg is only a MIN;
// waves_per_eu(4,4) also caps the MAX at 4 waves/EU (= our 1 block), so
// the budget is 128 VGPR and there is no occupancy reward for spilling.
#define FPS_DECL(i) float px##i, py##i, pz##i, dd##i;
#define FPS_LOAD(i)                    \
  {                                    \
    int n = tid + (i) * 1024;          \
    px##i = p[n * 3 + 0];              \
    py##i = p[n * 3 + 1];              \
    pz##i = p[n * 3 + 2];              \
    dd##i = INFINITY;                  \
  }
#define FPS_PIN(i) \
  asm volatile("" : "+v"(px##i), "+v"(py##i), "+v"(pz##i));
#define FPS_DIST(i)                                                              \
  {                                                                              \
    float dx = __fsub_rn(px##i, lx), dy = __fsub_rn(py##i, ly),                  \
          dz = __fsub_rn(pz##i, lz);                                             \
    float d = fmaf(dz, dz, fmaf(dx, dx, __fmul_rn(dy, dy)));                     \
    float nd = fminf(dd##i, d);                                                  \
    dd##i = nd;                                                                  \
    unsigned long long key =                                                     \
        ((unsigned long long)__float_as_uint(nd) << 32) |                        \
        (unsigned int)(ntid - (i) * 1024u);                                      \
    bk = (key > bk) ? key : bk;                                                  \
  }
#define FPS_SELW(i)                                  \
  if (jw == (i)) { ox = px##i; oy = py##i; oz = pz##i; }

__global__ __launch_bounds__(1024)
__attribute__((amdgpu_waves_per_eu(4, 4)))
void fps_kernel(const float* __restrict__ pos,
                int* __restrict__ samp,
                float* __restrict__ out) {
  const int b = blockIdx.x;
  const int tid = threadIdx.x;
  const float* p = pos + b * NPER * 3;
  __shared__ float lastpos[3];
  __shared__ unsigned long long slot[2];
  FPS_DECL(0) FPS_DECL(1) FPS_DECL(2) FPS_DECL(3)
  FPS_DECL(4) FPS_DECL(5) FPS_DECL(6) FPS_DECL(7)
  FPS_LOAD(0) FPS_LOAD(1) FPS_LOAD(2) FPS_LOAD(3)
  FPS_LOAD(4) FPS_LOAD(5) FPS_LOAD(6) FPS_LOAD(7)
  FPS_PIN(0) FPS_PIN(1) FPS_PIN(2) FPS_PIN(3)
  FPS_PIN(4) FPS_PIN(5) FPS_PIN(6) FPS_PIN(7)
  const unsigned int ntid = ~(unsigned int)tid;
  if (tid == 0) {
    slot[0] = 0ull;
    slot[1] = 0ull;
    lastpos[0] = px0;
    lastpos[1] = py0;
    lastpos[2] = pz0;
    samp[b * MPER] = 0;
    out[NEWPOS_OFF + (b * MPER) * 3 + 0] = px0;
    out[NEWPOS_OFF + (b * MPER) * 3 + 1] = py0;
    out[NEWPOS_OFF + (b * MPER) * 3 + 2] = pz0;
  }
  __syncthreads();
  for (int s = 1; s < MPER; ++s) {
    const float lx = lastpos[0], ly = lastpos[1], lz = lastpos[2];
    unsigned long long bk = 0ull;
    FPS_DIST(0) FPS_DIST(1) FPS_DIST(2) FPS_DIST(3)
    FPS_DIST(4) FPS_DIST(5) FPS_DIST(6) FPS_DIST(7)
#pragma unroll
    for (int off = 1; off < 64; off <<= 1) {
      unsigned long long o = __shfl_xor(bk, off, 64);
      bk = (o > bk) ? o : bk;
    }
    if ((tid & 63) == 0) atomicMax(&slot[s & 1], bk);
    __syncthreads();
    unsigned long long w = slot[s & 1];
    int widx = (int)(~(unsigned int)(w & 0xFFFFFFFFull));
    if (tid == 0) slot[(s & 1) ^ 1] = 0ull;
    if (tid == (widx & 1023)) {
      const int jw = widx >> 10;
      float ox = px0, oy = py0, oz = pz0;
      FPS_SELW(1) FPS_SELW(2) FPS_SELW(3)
      FPS_SELW(4) FPS_SELW(5) FPS_SELW(6) FPS_SELW(7)
      lastpos[0] = ox;
      lastpos[1] = oy;
      lastpos[2] = oz;
      samp[b * MPER + s] = widx;
      out[NEWPOS_OFF + (b * MPER + s) * 3 + 0] = ox;
      out[NEWPOS_OFF + (b * MPER + s) * 3 + 1] = oy;
      out[NEWPOS_OFF + (b * MPER + s) * 3 + 2] = oz;
    }
    __syncthreads();
  }
}

// ---------------- kNN: Eigen-style ascending fma dot, expand-formula d2 ----------------
__global__ __launch_bounds__(256) void knn_kernel(const float* __restrict__ pos,
                                                  const float* __restrict__ sqp,
                                                  const int* __restrict__ samp,
                                                  const float* __restrict__ h,
                                                  float* __restrict__ out) {
  const int q = blockIdx.x;
  const int b = q >> 12;
  const int tid = threadIdx.x;
  const int gbase = b * NPER;
  __shared__ float dist[NPER];  // 32 KB
  __shared__ unsigned long long slot[2];
  __shared__ int nbr[16];
  const int sidx = samp[q];
  const float qx = pos[(gbase + sidx) * 3 + 0];
  const float qy = pos[(gbase + sidx) * 3 + 1];
  const float qz = pos[(gbase + sidx) * 3 + 2];
  const float sqq = sqp[gbase + sidx];
  if (tid == 0) {
    slot[0] = ~0ull;
    slot[1] = ~0ull;
  }
  unsigned long long lkey = ~0ull;
  for (int i = 0; i < 32; ++i) {
    int n = tid + i * 256;
    int g = gbase + n;
    // Eigen gebp: fma(q2,p2, fma(q1,p1, rn(q0*p0)))
    float dot = fmaf(qz, pos[g * 3 + 2],
                     fmaf(qy, pos[g * 3 + 1], __fmul_rn(qx, pos[g * 3 + 0])));
    // (sq_q + sq_p) - 2*dot, each op rounded
    float d2 = __fsub_rn(__fadd_rn(sqq, sqp[g]), __fmul_rn(2.0f, dot));
    dist[n] = d2;
    unsigned int ub = __float_as_uint(d2);
    ub = (ub & 0x80000000u) ? ~ub : (ub | 0x80000000u);  // monotone float->uint
    unsigned long long key = ((unsigned long long)ub << 32) | (unsigned int)n;
    lkey = (key < lkey) ? key : lkey;
  }
  __syncthreads();
  for (int r = 0; r < 16; ++r) {
    unsigned long long wk = lkey;
#pragma unroll
    for (int off = 1; off < 64; off <<= 1) {
      unsigned long long o = __shfl_xor(wk, off, 64);
      wk = (o < wk) ? o : wk;
    }
    if ((tid & 63) == 0) atomicMin(&slot[r & 1], wk);
    __syncthreads();
    unsigned long long w = slot[r & 1];
    int n = (int)(unsigned int)(w & 0xFFFFFFFFull);
    if (tid == 0) {
      nbr[r] = n;
      slot[(r & 1) ^ 1] = ~0ull;
    }
    if (tid == (n & 255)) {  // owner removes it and refreshes its local min
      dist[n] = INFINITY;
      lkey = ~0ull;
      for (int i = 0; i < 32; ++i) {
        int nn = tid + i * 256;
        unsigned int ub = __float_as_uint(dist[nn]);
        ub = (ub & 0x80000000u) ? ~ub : (ub | 0x80000000u);
        unsigned long long kk = ((unsigned long long)ub << 32) | (unsigned int)nn;
        lkey = (kk < lkey) ? kk : lkey;
      }
    }
    __syncthreads();
  }
  if (tid < COUT) {
    float mx = -INFINITY;
#pragma unroll
    for (int r = 0; r < 16; ++r) mx = fmaxf(mx, h[(gbase + nbr[r]) * 128 + tid]);
    out[q * 128 + tid] = mx;
  }
}

extern "C" void kernel_launch(void* const* d_in, const int* in_sizes, int n_in,
                              void* d_out, int out_size, void* d_ws, size_t ws_size,
                              hipStream_t stream) {
  (void)in_sizes; (void)n_in; (void)out_size; (void)ws_size;
  const float* x     = (const float*)d_in[0];
  const float* pos   = (const float*)d_in[1];
  const float* W     = (const float*)d_in[3];
  const float* bias  = (const float*)d_in[4];
  const float* gamma = (const float*)d_in[5];
  const float* beta  = (const float*)d_in[6];
  float* out = (float*)d_out;
  char* ws = (char*)d_ws;
  float* h     = (float*)(ws + WS_H);
  float* sqp   = (float*)(ws + WS_SQP);
  int*   samp  = (int*)(ws + WS_SAMP);
  float* part  = (float*)(ws + WS_PART);
  float* part2 = (float*)(ws + WS_PART2);
  float* stat  = (float*)(ws + WS_STAT);

  misc_kernel<<<dim3(32), dim3(1024), 0, stream>>>(pos, sqp, out);
  matmul_kernel<<<dim3(2048), dim3(256), 0, stream>>>(x, W, bias, h);
  stats_kernel<<<dim3(64), dim3(256), 0, stream>>>(h, part, part2);
  finalize_kernel<<<dim3(1), dim3(128), 0, stream>>>(part, part2, stat);
  bngelu_kernel<<<dim3(2048), dim3(256), 0, stream>>>(h, stat, gamma, beta);
  fps_kernel<<<dim3(NB), dim3(1024), 0, stream>>>(pos, samp, out);
  knn_kernel<<<dim3(MTOT), dim3(256), 0, stream>>>(pos, sqp, samp, h, out);
}